// Round 3
// baseline (168.206 us; speedup 1.0000x reference)
//
#include <hip/hip_runtime.h>
#include <stdint.h>

typedef unsigned short u16;
typedef __attribute__((ext_vector_type(8))) short short8;
typedef __attribute__((ext_vector_type(4))) float f32x4;

__device__ __forceinline__ float bf2f(u16 u) {
    union { unsigned int i; float f; } v;
    v.i = ((unsigned int)u) << 16;
    return v.f;
}
__device__ __forceinline__ u16 f2bf(float f) {
    union { float f; unsigned int i; } v; v.f = f;
    unsigned int b = v.i;
    return (u16)((b + 0x7FFFu + ((b >> 16) & 1u)) >> 16);
}

// async global->LDS, 16B per lane. LDS dest must be wave-uniform base; HW adds lane*16.
typedef const __attribute__((address_space(1))) void* as1cv;
typedef __attribute__((address_space(3))) void* as3v;
__device__ __forceinline__ void gload16(const void* g, void* l) {
    __builtin_amdgcn_global_load_lds((as1cv)g, (as3v)l, 16, 0, 0);
}

// ---------------------------------------------------------------------------
// Kernel 0 (merged prep): blocks [0,4096) convert Q,K fp32->bf16;
// blocks [4096,4160) convert+transpose the 4 weight matrices.
// ---------------------------------------------------------------------------
__global__ __launch_bounds__(256) void prep(
    const float* __restrict__ Q, const float* __restrict__ K,
    const float* __restrict__ Wq, const float* __restrict__ Wk,
    const float* __restrict__ Wv, const float* __restrict__ Wo,
    u16* __restrict__ Qb, u16* __restrict__ Kb,
    u16* __restrict__ Tq, u16* __restrict__ Tk,
    u16* __restrict__ Tv, u16* __restrict__ To)
{
    __shared__ u16 ts[64][65];
    int bi = blockIdx.x;
    int t = threadIdx.x;
    if (bi < 4096) {
        const float* src = (bi < 2048) ? Q : K;
        u16* dst = (bi < 2048) ? Qb : Kb;
        int blk = bi & 2047;
        size_t i = ((size_t)blk * 256 + t) * 8;
        float4 a = *reinterpret_cast<const float4*>(src + i);
        float4 b = *reinterpret_cast<const float4*>(src + i + 4);
        u16 o[8] = {f2bf(a.x), f2bf(a.y), f2bf(a.z), f2bf(a.w),
                    f2bf(b.x), f2bf(b.y), f2bf(b.z), f2bf(b.w)};
        *reinterpret_cast<uint4*>(dst + i) = *reinterpret_cast<const uint4*>(o);
        return;
    }
    int wi = bi - 4096;               // 0..63
    int wsel = wi >> 4;               // which weight
    const float* W = wsel == 0 ? Wq : wsel == 1 ? Wk : wsel == 2 ? Wv : Wo;
    u16*        T  = wsel == 0 ? Tq : wsel == 1 ? Tk : wsel == 2 ? Tv : To;
    int k0 = ((wi >> 2) & 3) * 64, n0 = (wi & 3) * 64;
    int r = t >> 2, cq = (t & 3) * 16;
    const float4* src = reinterpret_cast<const float4*>(W + (k0 + r) * 256 + n0 + cq);
    for (int u = 0; u < 4; ++u) {
        float4 v = src[u];
        int c = cq + u * 4;
        ts[r][c + 0] = f2bf(v.x); ts[r][c + 1] = f2bf(v.y);
        ts[r][c + 2] = f2bf(v.z); ts[r][c + 3] = f2bf(v.w);
    }
    __syncthreads();
    u16* dst = T + (n0 + r) * 256 + k0 + cq;
    for (int u = 0; u < 16; ++u) dst[u] = ts[cq + u][r];
}

// ---------------------------------------------------------------------------
// GEMM core: bf16 A [16384,256] @ Wt[n][k] bf16 + bias -> C (bf16 or f32)
// 128x128 tile, BK=64, global_load_lds x16B staging, unpadded LDS.
// ---------------------------------------------------------------------------
template <bool F32OUT>
__device__ __forceinline__ void gemm_core(
    const u16* __restrict__ Ab, const u16* __restrict__ Wt,
    const float* __restrict__ bias, void* __restrict__ Cv,
    int row0, int col0)
{
    __shared__ u16 As[128 * 64];
    __shared__ u16 Bs[128 * 64];

    int t = threadIdx.x;
    int lane = t & 63, w = t >> 6;
    int wr = (w >> 1) * 64, wc = (w & 1) * 64;
    int qd = lane >> 4, md = lane & 15;

    int srow = w * 32 + (lane >> 3);
    int scol = (lane & 7) * 8;

    f32x4 acc[4][4] = {};

    for (int kt = 0; kt < 256; kt += 64) {
#pragma unroll
        for (int u = 0; u < 4; ++u) {
            int r = srow + u * 8;
            gload16(Ab + (size_t)(row0 + r) * 256 + kt + scol,
                    (char*)As + (w * 4 + u) * 1024);
            gload16(Wt + (size_t)(col0 + r) * 256 + kt + scol,
                    (char*)Bs + (w * 4 + u) * 1024);
        }
        __syncthreads();
#pragma unroll
        for (int ks = 0; ks < 64; ks += 32) {
            short8 af[4], bf[4];
#pragma unroll
            for (int i = 0; i < 4; ++i)
                af[i] = *reinterpret_cast<const short8*>(
                    &As[(wr + i * 16 + md) * 64 + ks + qd * 8]);
#pragma unroll
            for (int j = 0; j < 4; ++j)
                bf[j] = *reinterpret_cast<const short8*>(
                    &Bs[(wc + j * 16 + md) * 64 + ks + qd * 8]);
#pragma unroll
            for (int i = 0; i < 4; ++i)
#pragma unroll
                for (int j = 0; j < 4; ++j)
                    acc[i][j] = __builtin_amdgcn_mfma_f32_16x16x32_bf16(
                        af[i], bf[j], acc[i][j], 0, 0, 0);
        }
        __syncthreads();
    }

#pragma unroll
    for (int i = 0; i < 4; ++i)
#pragma unroll
        for (int j = 0; j < 4; ++j) {
            int col = col0 + wc + j * 16 + md;
            float b = bias[col];
#pragma unroll
            for (int r = 0; r < 4; ++r) {
                int row = row0 + wr + i * 16 + qd * 4 + r;
                if (F32OUT)
                    ((float*)Cv)[(size_t)row * 256 + col] = acc[i][j][r] + b;
                else
                    ((u16*)Cv)[(size_t)row * 256 + col] = f2bf(acc[i][j][r] + b);
            }
        }
}

__global__ __launch_bounds__(256) void gemm_proj(
    const u16* __restrict__ Qb, const u16* __restrict__ Kb,
    const u16* __restrict__ Wtq, const u16* __restrict__ Wtk, const u16* __restrict__ Wtv,
    const float* __restrict__ bq, const float* __restrict__ bk, const float* __restrict__ bv,
    u16* __restrict__ Qh, u16* __restrict__ Kh, u16* __restrict__ Vh)
{
    int z = blockIdx.z;
    const u16*   A    = (z == 0) ? Qb  : Kb;
    const u16*   Wt   = (z == 0) ? Wtq : (z == 1) ? Wtk : Wtv;
    const float* bias = (z == 0) ? bq  : (z == 1) ? bk  : bv;
    u16*         C    = (z == 0) ? Qh  : (z == 1) ? Kh  : Vh;
    gemm_core<false>(A, Wt, bias, C, blockIdx.x * 128, blockIdx.y * 128);
}

__global__ __launch_bounds__(256) void gemm_out(
    const u16* __restrict__ A, const u16* __restrict__ Wt,
    const float* __restrict__ bias, float* __restrict__ Cout)
{
    gemm_core<true>(A, Wt, bias, Cout, blockIdx.x * 128, blockIdx.y * 128);
}

// ---------------------------------------------------------------------------
// Kernel 3: gather attention. One block (256 thr) per 2 rows.
// NO K/V LDS staging (zero intra-row reuse); streamed dword-vectorized loads;
// precomputed neighbour byte-offsets; LDS ~4.3 KB -> wave-cap occupancy.
// ---------------------------------------------------------------------------
__global__ __launch_bounds__(256) void attn(
    const u16* __restrict__ Qh, const u16* __restrict__ Kh, const u16* __restrict__ Vh,
    const int* __restrict__ nbr, u16* __restrict__ AVb)
{
    __shared__ float qs[2][256];
    __shared__ float as_[2][256];
    __shared__ int jb[2][32];          // neighbour row byte-offsets

    int t = threadIdx.x;
    int row0 = blockIdx.x * 2;
    int b = row0 >> 13;

    // load Q (2 rows x 256 ch): 1 dword (2 ch) per thread, unpack to f32 LDS
    {
        int r = t >> 7, c = (t & 127) * 2;
        unsigned int v = *reinterpret_cast<const unsigned int*>(
            Qh + (size_t)(row0 + r) * 256 + c);
        union { unsigned int i; float f; } lo, hi;
        lo.i = v << 16; hi.i = v & 0xffff0000u;
        qs[r][c] = lo.f; qs[r][c + 1] = hi.f;
    }
    if (t < 64) {
        int r = t >> 5, j = t & 31;
        int ji = nbr[(size_t)(row0 + r) * 32 + j];
        jb[r][j] = ((b << 13) + ji) << 9;   // row * 256 ch * 2 B
    }
    __syncthreads();

    // scores: thread t -> (h = t>>5, j = t&31), both rows sequentially
    int h = t >> 5, j = t & 31;
#pragma unroll
    for (int r = 0; r < 2; ++r) {
        const char* kp = (const char*)Kh + jb[r][j] + h * 64;
        uint4 kw[4];
        kw[0] = *reinterpret_cast<const uint4*>(kp);
        kw[1] = *reinterpret_cast<const uint4*>(kp + 16);
        kw[2] = *reinterpret_cast<const uint4*>(kp + 32);
        kw[3] = *reinterpret_cast<const uint4*>(kp + 48);
        const float* q = &qs[r][h * 32];
        float e = 0.f;
#pragma unroll
        for (int cq4 = 0; cq4 < 4; ++cq4) {
            unsigned int wds[4] = {kw[cq4].x, kw[cq4].y, kw[cq4].z, kw[cq4].w};
#pragma unroll
            for (int u = 0; u < 4; ++u) {
                union { unsigned int i; float f; } lo, hi;
                lo.i = wds[u] << 16; hi.i = wds[u] & 0xffff0000u;
                e += q[cq4 * 8 + u * 2] * lo.f + q[cq4 * 8 + u * 2 + 1] * hi.f;
            }
        }
        e *= 0.0625f;  // 1/sqrt(256)
        float m = e;
        for (int off = 16; off; off >>= 1) m = fmaxf(m, __shfl_xor(m, off, 32));
        float p = __expf(e - m);
        float s = p;
        for (int off = 16; off; off >>= 1) s += __shfl_xor(s, off, 32);
        as_[r][t] = p / s;
    }
    __syncthreads();

    // AV: thread t -> row r = t>>7, dword-channel c = t&127 (chs 2c, 2c+1)
    {
        int r = t >> 7, c = t & 127, hh = c >> 4;
        const float* aw = &as_[r][hh * 32];
        float a0 = 0.f, a1 = 0.f;
#pragma unroll
        for (int jj = 0; jj < 32; ++jj) {
            unsigned int v = *reinterpret_cast<const unsigned int*>(
                (const char*)Vh + jb[r][jj] + c * 4);
            union { unsigned int i; float f; } lo, hi;
            lo.i = v << 16; hi.i = v & 0xffff0000u;
            float wgt = aw[jj];
            a0 += wgt * lo.f; a1 += wgt * hi.f;
        }
        u16 o[2] = {f2bf(a0), f2bf(a1)};
        *reinterpret_cast<unsigned int*>(AVb + (size_t)(row0 + r) * 256 + c * 2) =
            *reinterpret_cast<const unsigned int*>(o);
    }
}

// ---------------------------------------------------------------------------
extern "C" void kernel_launch(void* const* d_in, const int* in_sizes, int n_in,
                              void* d_out, int out_size, void* d_ws, size_t ws_size,
                              hipStream_t stream) {
    const float* Q   = (const float*)d_in[0];
    const float* K   = (const float*)d_in[1];
    const int*   nbr = (const int*)d_in[2];
    const float* Wq  = (const float*)d_in[3];
    const float* bq  = (const float*)d_in[4];
    const float* Wk  = (const float*)d_in[5];
    const float* bk  = (const float*)d_in[6];
    const float* Wv  = (const float*)d_in[7];
    const float* bv  = (const float*)d_in[8];
    const float* Wo  = (const float*)d_in[9];
    const float* bo  = (const float*)d_in[10];
    float* out = (float*)d_out;

    char* ws = (char*)d_ws;
    size_t off = 0;
    auto alloc = [&](size_t bytes) -> void* {
        void* p = ws + off;
        off += (bytes + 255) & ~(size_t)255;
        return p;
    };
    const size_t MN = 16384;  // B*N == B*M
    u16* Wtq = (u16*)alloc(256 * 256 * 2);
    u16* Wtk = (u16*)alloc(256 * 256 * 2);
    u16* Wtv = (u16*)alloc(256 * 256 * 2);
    u16* Wto = (u16*)alloc(256 * 256 * 2);
    u16* Qb  = (u16*)alloc(MN * 256 * 2);
    u16* Kb  = (u16*)alloc(MN * 256 * 2);
    u16* Qh  = (u16*)alloc(MN * 256 * 2);
    u16* Kh  = (u16*)alloc(MN * 256 * 2);
    u16* Vh  = (u16*)alloc(MN * 256 * 2);
    u16* AVb = (u16*)alloc(MN * 256 * 2);

    prep<<<dim3(4160), 256, 0, stream>>>(Q, K, Wq, Wk, Wv, Wo,
                                         Qb, Kb, Wtq, Wtk, Wtv, Wto);
    gemm_proj<<<dim3(128, 2, 3), 256, 0, stream>>>(Qb, Kb, Wtq, Wtk, Wtv,
                                                   bq, bk, bv, Qh, Kh, Vh);
    attn<<<dim3(8192), 256, 0, stream>>>(Qh, Kh, Vh, nbr, AVb);
    gemm_out<<<dim3(128, 2, 1), 256, 0, stream>>>(AVb, Wto, bo, out);
}